// Round 6
// baseline (156.163 us; speedup 1.0000x reference)
//
#include <hip/hip_runtime.h>
#include <math.h>

#define BB 4
#define NN 1024
#define FF 128
#define DD 128
#define FOBS 32
#define NBLK 256

typedef __attribute__((ext_vector_type(8))) short bfrag;   // 8 bf16 = 4 VGPR
typedef __attribute__((ext_vector_type(4))) float ffrag;   // 4 f32 acc
typedef __attribute__((ext_vector_type(4))) unsigned short us4;

__device__ __forceinline__ unsigned short f2bf(float x) {
    unsigned u = __builtin_bit_cast(unsigned, x);
    u += 0x7fffu + ((u >> 16) & 1u);              // RNE
    return (unsigned short)(u >> 16);
}
__device__ __forceinline__ void gload16(const void* g, void* l) {
    __builtin_amdgcn_global_load_lds((const __attribute__((address_space(1))) unsigned*)g,
                                     (__attribute__((address_space(3))) unsigned*)l, 16, 0, 0);
}
// grid barrier: leader release-fence + atomic arrive + spin + acquire-fence.
__device__ __forceinline__ void gbar(unsigned* cnt) {
    __syncthreads();                               // drains each thread's vm/lgkm ops
    if (threadIdx.x == 0) {
        __threadfence();                           // release (L2 wb, device scope)
        __hip_atomic_fetch_add(cnt, 1u, __ATOMIC_RELAXED, __HIP_MEMORY_SCOPE_AGENT);
        while (__hip_atomic_load(cnt, __ATOMIC_RELAXED, __HIP_MEMORY_SCOPE_AGENT) < NBLK)
            __builtin_amdgcn_s_sleep(8);
        __threadfence();                           // acquire (L1/L2 inv)
    }
    __syncthreads();
}

// ---------------------------------------------------------------- ga phase
// acc[f][n] = sum_k T[f][k] * S[k][n]  (S symmetric -> stage S rows contiguous)
// LAST=0: Tout[f][n] = bf16(acc);  LAST=1: Hs[n][f] = relu(acc) f32.
template <int LAST>
__device__ __forceinline__ void ga_phase(const unsigned short* __restrict__ Sb,
                                         const unsigned short* __restrict__ Tin,
                                         unsigned short* __restrict__ Tout,
                                         float* __restrict__ HsB,
                                         int n0, int tid, char* smem) {
    unsigned short* T_s = (unsigned short*)smem;              // 3 x 128x64
    unsigned short* S_s = (unsigned short*)(smem + 49152);    // 3 x 16x64
    auto stageT = [&](int buf, int kt) {          // uniform 5 gload16 per thread
#pragma unroll
        for (int p = 0; p < 4; p++) {
            int c = p * 256 + tid, row = c >> 3, kc = c & 7;
            gload16(Tin + (size_t)row * NN + kt + ((kc ^ (row & 7)) * 8),
                    T_s + (size_t)buf * (128 * 64) + (size_t)c * 8);
        }
        int c = tid & 127, row = c >> 3, kc = c & 7;   // tid>=128 duplicates, benign
        gload16(Sb + (size_t)(n0 + row) * NN + kt + ((kc ^ (row & 7)) * 8),
                S_s + (size_t)buf * (16 * 64) + (size_t)c * 8);
    };
    stageT(0, 0);
    stageT(1, 64);

    int w = tid >> 6, l = tid & 63, lr = l & 15, lg = l >> 4;
    ffrag acc[2] = {};
    int cur = 0, sb = 2;
    for (int t = 0; t < 16; t++) {
        if (t <= 13) stageT(sb, (t + 2) * 64);
        if (t < 14)       asm volatile("s_waitcnt vmcnt(10)" ::: "memory");
        else if (t == 14) asm volatile("s_waitcnt vmcnt(5)"  ::: "memory");
        else              asm volatile("s_waitcnt vmcnt(0)"  ::: "memory");
        __builtin_amdgcn_s_barrier();
        asm volatile("" ::: "memory");
        const unsigned short* Tc = T_s + (size_t)cur * (128 * 64);
        const unsigned short* Sc = S_s + (size_t)cur * (16 * 64);
#pragma unroll
        for (int ks = 0; ks < 2; ks++) {
            int k0 = ks * 32 + lg * 8;
            bfrag a[2], bb;
#pragma unroll
            for (int rb = 0; rb < 2; rb++) {
                int row = w * 32 + rb * 16 + lr;
                int byt = (row * 128 + k0 * 2) ^ ((row & 7) << 4);
                a[rb] = *(const bfrag*)((const char*)Tc + byt);
            }
            {
                int row = lr;
                int byt = (row * 128 + k0 * 2) ^ ((row & 7) << 4);
                bb = *(const bfrag*)((const char*)Sc + byt);
            }
#pragma unroll
            for (int rb = 0; rb < 2; rb++)
                acc[rb] = __builtin_amdgcn_mfma_f32_16x16x32_bf16(a[rb], bb, acc[rb], 0, 0, 0);
        }
        asm volatile("s_waitcnt lgkmcnt(0)" ::: "memory");
        __builtin_amdgcn_s_barrier();
        cur = (cur == 2) ? 0 : cur + 1;
        sb = (sb == 2) ? 0 : sb + 1;
    }
    if (LAST) {
#pragma unroll
        for (int rb = 0; rb < 2; rb++) {
            int f0 = w * 32 + rb * 16 + lg * 4;
            float v[4];
#pragma unroll
            for (int r = 0; r < 4; r++) v[r] = fmaxf(acc[rb][r], 0.f);
            *(float4*)&HsB[(size_t)(n0 + lr) * DD + f0] = make_float4(v[0], v[1], v[2], v[3]);
        }
    } else {
#pragma unroll
        for (int rb = 0; rb < 2; rb++)
#pragma unroll
            for (int r = 0; r < 4; r++) {
                int f = w * 32 + rb * 16 + lg * 4 + r;
                Tout[(size_t)f * NN + n0 + lr] = f2bf(acc[rb][r]);
            }
    }
}

// ---------------------------------------------------------------- fused persistent kernel
__global__ __launch_bounds__(256, 1) void fused_kernel(
    const float* __restrict__ X, const float* __restrict__ a_link,
    const float* __restrict__ W0, const float* __restrict__ W1, const float* __restrict__ W2,
    float* __restrict__ As, float* __restrict__ Xo, float* __restrict__ Hs,
    float* __restrict__ Ds,
    unsigned short* __restrict__ Sbf, unsigned short* __restrict__ Xbf,
    unsigned short* __restrict__ TtX, unsigned short* __restrict__ TtY,
    unsigned short* __restrict__ W01t, unsigned short* __restrict__ W2t,
    float* __restrict__ Pp, unsigned* cnt, int usews)
{
    __shared__ __align__(16) char smem[77824];
    int tid = threadIdx.x;
    int bid = blockIdx.x;

    // ================= phase A: adjacency (4 tiles/block) + prep =================
    {
        float* hi   = (float*)smem;                  // [64][33]
        float* hj   = (float*)(smem + 8448);         // [64][33]
        float* av   = (float*)(smem + 16896);        // [32]
        float* part = (float*)(smem + 17024);        // [64][16]
        if (tid < FOBS) av[tid] = a_link[tid];
        for (int it = 0; it < 4; it++) {
            int t = bid * 4 + it;
            int bt = t >> 8, rem = t & 255;
            int i0 = (rem >> 4) * 64, j0 = (rem & 15) * 64;
            const float* Xb = X + (size_t)bt * NN * FF;
            __syncthreads();                         // LDS reuse + av visible
            if (j0 == 0) {                           // Xo passthrough for this row-panel
#pragma unroll
                for (int p = 0; p < 8; p++) {
                    int c = p * 256 + tid, r = c >> 5, qq = c & 31;
                    *(float4*)&Xo[((size_t)bt * NN + i0 + r) * FF + qq * 4] =
                        *(const float4*)&Xb[(size_t)(i0 + r) * FF + qq * 4];
                }
            }
#pragma unroll
            for (int lq = 0; lq < 8; lq++) {
                int idx = lq * 256 + tid;
                int r = idx >> 5, f = idx & 31;
                hi[r * 33 + f] = Xb[(size_t)(i0 + r) * FF + f];
                hj[r * 33 + f] = Xb[(size_t)(j0 + r) * FF + f];
            }
            __syncthreads();
            int ty = tid >> 4, tx = tid & 15;
            int ir = ty * 4, jc = tx * 4;
            float acc[4][4] = {};
#pragma unroll
            for (int f = 0; f < FOBS; f++) {
                float a = av[f];
                float x[4], y[4];
#pragma unroll
                for (int r = 0; r < 4; r++) x[r] = hi[(ir + r) * 33 + f];
#pragma unroll
                for (int c = 0; c < 4; c++) y[c] = hj[(jc + c) * 33 + f];
#pragma unroll
                for (int r = 0; r < 4; r++)
#pragma unroll
                    for (int c = 0; c < 4; c++)
                        acc[r][c] += fabsf(x[r] - y[c]) * a;
            }
            float* Ab = As + (size_t)bt * NN * NN;
#pragma unroll
            for (int r = 0; r < 4; r++) {
                int gi = i0 + ir + r;
                float vv[4]; float rs = 0.f;
#pragma unroll
                for (int c = 0; c < 4; c++) {
                    int gj = j0 + jc + c;
                    float sg = 1.f / (1.f + __expf(-acc[r][c]));
                    vv[c] = (gi == gj) ? 0.f : sg;
                    rs += vv[c];
                }
                *(float4*)&Ab[(size_t)gi * NN + (j0 + jc)] = make_float4(vv[0], vv[1], vv[2], vv[3]);
                part[(ir + r) * 16 + tx] = rs;
            }
            __syncthreads();
            if (tid < 64) {
                float s = 0.f;
#pragma unroll
                for (int k = 0; k < 16; k++) s += part[tid * 16 + k];
                Pp[((size_t)bt * NN + i0 + tid) * 16 + (rem & 15)] = s;
            }
        }
        // prep (disjoint block ranges)
        if (bid < 16) {                              // W01t[g][f] = (W0@W1)[f][g], f32 acc
#pragma unroll
            for (int q = 0; q < 4; q++) {
                int e = q * 256 + tid;
                int g = bid * 8 + (e >> 7), f = e & 127;
                float s = 0.f;
                for (int h = 0; h < 128; h++) s += W0[f * 128 + h] * W1[h * 128 + g];
                W01t[g * 128 + f] = f2bf(s);
            }
        } else if (bid < 32) {                       // W2t[f2][g] = W2[g][f2]
#pragma unroll
            for (int q = 0; q < 4; q++) {
                int e = (bid - 16) * 1024 + q * 256 + tid;
                int f2 = e >> 7, g = e & 127;
                W2t[e] = f2bf(W2[g * 128 + f2]);
            }
        } else if (bid < 96) {                       // Xbf cast
#pragma unroll
            for (int q = 0; q < 8; q++) {
                size_t i4 = (size_t)(bid - 32) * 2048 + q * 256 + tid;
                float4 v = *(const float4*)&X[i4 * 4];
                us4 o; o[0] = f2bf(v.x); o[1] = f2bf(v.y); o[2] = f2bf(v.z); o[3] = f2bf(v.w);
                *(us4*)&Xbf[i4 * 4] = o;
            }
        }
    }
    gbar(cnt + 0);

    // ================= phase B: dinv + S + T0 (+Ds-zero) =================
    int b = bid >> 6, n0 = (bid & 63) * 16;
    {
        float* dinvF         = (float*)smem;                       // [1024]
        unsigned short* W01s = (unsigned short*)(smem + 4096);     // 128x128 swz
        unsigned short* W2s  = (unsigned short*)(smem + 36864);    // 128x128 swz
        unsigned short* Xps  = (unsigned short*)(smem + 69632);    // 16x128 swz
        unsigned short* Ps   = (unsigned short*)(smem + 73728);    // 16x128 swz
        const unsigned short* Xb = Xbf + (size_t)b * NN * DD;
#pragma unroll
        for (int p = 0; p < 8; p++) {
            int c = p * 256 + tid, row = c >> 4, kc = c & 15;
            gload16(W01t + (size_t)row * 128 + ((kc ^ (row & 7)) * 8), W01s + (size_t)c * 8);
        }
#pragma unroll
        for (int p = 0; p < 8; p++) {
            int c = p * 256 + tid, row = c >> 4, kc = c & 15;
            gload16(W2t + (size_t)row * 128 + ((kc ^ (row & 7)) * 8), W2s + (size_t)c * 8);
        }
        {
            int c = tid, row = c >> 4, kc = c & 15;
            gload16(Xb + (size_t)(n0 + row) * 128 + ((kc ^ (row & 7)) * 8), Xps + (size_t)c * 8);
        }
#pragma unroll
        for (int rr = 0; rr < 4; rr++) {             // full dinv vector for batch b
            int row = tid * 4 + rr;
            const float* pp = Pp + ((size_t)b * NN + row) * 16;
            float s = 0.f;
#pragma unroll
            for (int k2 = 0; k2 < 16; k2++) s += pp[k2];
            dinvF[row] = rsqrtf(1.f + s);
        }
        __syncthreads();
        {                                            // S rows n0..n0+15 (diag = dinv^2)
            int r = tid >> 4, cg = tid & 15;
            int gi = n0 + r;
            const float* Ar = As + ((size_t)b * NN + gi) * NN;
            unsigned short* Sr = Sbf + ((size_t)b * NN + gi) * NN;
            float di = dinvF[gi];
#pragma unroll
            for (int c4 = 0; c4 < 16; c4++) {
                int col = cg * 4 + c4 * 64;
                float4 a4 = *(const float4*)&Ar[col];
                us4 o;
                o[0] = f2bf(di * dinvF[col + 0] * (a4.x + ((col + 0) == gi ? 1.f : 0.f)));
                o[1] = f2bf(di * dinvF[col + 1] * (a4.y + ((col + 1) == gi ? 1.f : 0.f)));
                o[2] = f2bf(di * dinvF[col + 2] * (a4.z + ((col + 2) == gi ? 1.f : 0.f)));
                o[3] = f2bf(di * dinvF[col + 3] * (a4.w + ((col + 3) == gi ? 1.f : 0.f)));
                *(us4*)&Sr[col] = o;
            }
        }
        if (usews) {                                 // Ds output zeros (Ds not scratch)
            float4* Z = (float4*)Ds;
#pragma unroll
            for (int q = 0; q < 16; q++)
                Z[(size_t)bid * 4096 + q * 256 + tid] = make_float4(0.f, 0.f, 0.f, 0.f);
        }
        int w = tid >> 6, l = tid & 63, lr = l & 15, lg = l >> 4;
        ffrag pacc[2] = {};                          // P[g][n] = (Xp @ W01)
#pragma unroll
        for (int ks = 0; ks < 4; ks++) {
            int k0 = ks * 32 + lg * 8;
            bfrag a[2], bb;
#pragma unroll
            for (int rb = 0; rb < 2; rb++) {
                int row = w * 32 + rb * 16 + lr;
                int byt = (row * 256 + k0 * 2) ^ ((row & 7) << 4);
                a[rb] = *(const bfrag*)((const char*)W01s + byt);
            }
            {
                int byt = (lr * 256 + k0 * 2) ^ ((lr & 7) << 4);
                bb = *(const bfrag*)((const char*)Xps + byt);
            }
#pragma unroll
            for (int rb = 0; rb < 2; rb++)
                pacc[rb] = __builtin_amdgcn_mfma_f32_16x16x32_bf16(a[rb], bb, pacc[rb], 0, 0, 0);
        }
#pragma unroll
        for (int rb = 0; rb < 2; rb++) {             // P -> LDS [n][g] swizzled
            int g0 = w * 32 + rb * 16 + lg * 4;
            us4 o;
#pragma unroll
            for (int r = 0; r < 4; r++) o[r] = f2bf(pacc[rb][r]);
            int byt = (lr * 256 + g0 * 2) ^ ((lr & 7) << 4);
            *(us4*)((char*)Ps + byt) = o;
        }
        __syncthreads();
        ffrag tacc[2] = {};                          // T0[f2][n] = (P @ W2)
#pragma unroll
        for (int ks = 0; ks < 4; ks++) {
            int k0 = ks * 32 + lg * 8;
            bfrag a2[2], b2;
#pragma unroll
            for (int rb = 0; rb < 2; rb++) {
                int row = w * 32 + rb * 16 + lr;
                int byt = (row * 256 + k0 * 2) ^ ((row & 7) << 4);
                a2[rb] = *(const bfrag*)((const char*)W2s + byt);
            }
            {
                int byt = (lr * 256 + k0 * 2) ^ ((lr & 7) << 4);
                b2 = *(const bfrag*)((const char*)Ps + byt);
            }
#pragma unroll
            for (int rb = 0; rb < 2; rb++)
                tacc[rb] = __builtin_amdgcn_mfma_f32_16x16x32_bf16(a2[rb], b2, tacc[rb], 0, 0, 0);
        }
        unsigned short* Tb = TtX + (size_t)b * DD * NN;
#pragma unroll
        for (int rb = 0; rb < 2; rb++)
#pragma unroll
            for (int r = 0; r < 4; r++) {
                int f2 = w * 32 + rb * 16 + lg * 4 + r;
                Tb[(size_t)f2 * NN + n0 + lr] = f2bf(tacc[rb][r]);
            }
    }
    gbar(cnt + 1);

    // ================= phases C/D/E: three S-GEMM hops =================
    const unsigned short* Sb = Sbf + (size_t)b * NN * NN;
    unsigned short* TXb = TtX + (size_t)b * DD * NN;
    unsigned short* TYb = TtY + (size_t)b * DD * NN;
    ga_phase<0>(Sb, TXb, TYb, nullptr, n0, tid, smem);
    gbar(cnt + 2);
    ga_phase<0>(Sb, TYb, TXb, nullptr, n0, tid, smem);
    gbar(cnt + 3);
    ga_phase<1>(Sb, TXb, nullptr, Hs + (size_t)b * NN * DD, n0, tid, smem);

    if (!usews) {                                    // scratch lived in Ds: zero after all reads
        gbar(cnt + 4);
        float4* Z = (float4*)Ds;
#pragma unroll
        for (int q = 0; q < 16; q++)
            Z[(size_t)bid * 4096 + q * 256 + tid] = make_float4(0.f, 0.f, 0.f, 0.f);
    }
}

// ---------------------------------------------------------------- launcher
extern "C" void kernel_launch(void* const* d_in, const int* in_sizes, int n_in,
                              void* d_out, int out_size, void* d_ws, size_t ws_size,
                              hipStream_t stream) {
    const float* X      = (const float*)d_in[0];
    const float* a_link = (const float*)d_in[1];
    const float* W0     = (const float*)d_in[2];
    const float* W1     = (const float*)d_in[3];
    const float* W2     = (const float*)d_in[4];
    float* out = (float*)d_out;

    const size_t HND = (size_t)BB * NN * DD;     // 524288
    const size_t HNN = (size_t)BB * NN * NN;     // 4194304
    float* Hs = out;
    float* As = out + HND;
    float* Xo = out + HND + HNN;
    float* Ds = out + 2 * HND + HNN;

    // scratch (bytes): Sbf 8388608 | Xbf 1048576 | TtX 1048576 | TtY 1048576
    //                  | W01t 32768 | W2t 32768 | Pp 262144 | cnt 64
    const size_t NEED = 11862080;
    bool usews = (ws_size >= NEED);
    char* scr = usews ? (char*)d_ws : (char*)Ds;

    unsigned short* Sbf  = (unsigned short*)(scr);
    unsigned short* Xbf  = (unsigned short*)(scr + 8388608);
    unsigned short* TtX  = (unsigned short*)(scr + 9437184);
    unsigned short* TtY  = (unsigned short*)(scr + 10485760);
    unsigned short* W01t = (unsigned short*)(scr + 11534336);
    unsigned short* W2t  = (unsigned short*)(scr + 11567104);
    float* Pp            = (float*)(scr + 11599872);
    unsigned* cnt        = (unsigned*)(scr + 11862016);

    hipMemsetAsync(cnt, 0, 64, stream);          // barrier counters: zeroed EVERY call
    fused_kernel<<<dim3(NBLK), dim3(256), 0, stream>>>(
        X, a_link, W0, W1, W2, As, Xo, Hs, Ds,
        Sbf, Xbf, TtX, TtY, W01t, W2t, Pp, cnt, usews ? 1 : 0);
}

// Round 7
// 56.662 us; speedup vs baseline: 2.7561x; 2.7561x over previous
//
#include <hip/hip_runtime.h>
#include <math.h>

#define BB 4
#define NN 1024
#define FF 128
#define DD 128
#define FOBS 32

typedef __attribute__((ext_vector_type(8))) short bfrag;   // 8 bf16 = 4 VGPR
typedef __attribute__((ext_vector_type(4))) float ffrag;   // 4 f32 acc
typedef __attribute__((ext_vector_type(4))) unsigned short us4;

__device__ __forceinline__ unsigned short f2bf(float x) {
    unsigned u = __builtin_bit_cast(unsigned, x);
    u += 0x7fffu + ((u >> 16) & 1u);              // RNE
    return (unsigned short)(u >> 16);
}
__device__ __forceinline__ void gload16(const void* g, void* l) {
    __builtin_amdgcn_global_load_lds((const __attribute__((address_space(1))) unsigned*)g,
                                     (__attribute__((address_space(3))) unsigned*)l, 16, 0, 0);
}

// ---------------------------------------------------------------- zero (f4)  (fallback)
__global__ __launch_bounds__(256) void zero_f4(float4* __restrict__ p, int n4) {
    int i = blockIdx.x * 256 + threadIdx.x;
    if (i < n4) p[i] = make_float4(0.f, 0.f, 0.f, 0.f);
}

// ---------------------------------------------------------------- adjacency (+prep +partials +Xo +Ds-zero)
// z 0..3 : A 64x64 tiles (f32 As + row-sum partials Pp)
// z 4    : prep — W01t[g][f]=(W0@W1)[f][g] bf16; W2t[f2][g]=W2[g][f2] bf16; Xbf cast
// z 5    : Ds-zero (only when scratch lives in d_ws)
__global__ __launch_bounds__(256) void adj_kernel(const float* __restrict__ X,
                                                  const float* __restrict__ a_link,
                                                  const float* __restrict__ W0,
                                                  const float* __restrict__ W1,
                                                  const float* __restrict__ W2,
                                                  float* __restrict__ As,
                                                  unsigned short* __restrict__ Xbf,
                                                  unsigned short* __restrict__ W01t,
                                                  unsigned short* __restrict__ W2t,
                                                  float* __restrict__ Pp,
                                                  float* __restrict__ Xo,
                                                  float* __restrict__ Zd) {
    int tid = threadIdx.x;
    if (blockIdx.z == 5) {                        // Ds-zero layer
        if (Zd) {
            int q = blockIdx.y * 16 + blockIdx.x; // 0..255
            float4* Z = (float4*)Zd;
#pragma unroll
            for (int p = 0; p < 16; p++)
                Z[(size_t)q * 4096 + p * 256 + tid] = make_float4(0.f, 0.f, 0.f, 0.f);
        }
        return;
    }
    if (blockIdx.z == 4) {                        // prep
        int q = (blockIdx.y * 16 + blockIdx.x) * 256 + tid;   // 0..65535
        if (q < 16384) {                          // W01t[g][f] = sum_h W0[f][h]*W1[h][g]
            int g = q >> 7, f = q & 127;
            float s = 0.f;
            for (int h = 0; h < 128; h++) s += W0[f * 128 + h] * W1[h * 128 + g];
            W01t[q] = f2bf(s);
        } else if (q < 32768) {                   // W2t[f2][g] = W2[g][f2]
            int e = q - 16384;
            int f2 = e >> 7, g = e & 127;
            W2t[e] = f2bf(W2[g * 128 + f2]);
        } else {                                  // Xbf cast: 32768 thr x 4 float4
            int u = q - 32768;
#pragma unroll
            for (int p = 0; p < 4; p++) {
                size_t i4 = (size_t)u + (size_t)p * 32768;
                float4 v = *(const float4*)&X[i4 * 4];
                us4 o; o[0] = f2bf(v.x); o[1] = f2bf(v.y); o[2] = f2bf(v.z); o[3] = f2bf(v.w);
                *(us4*)&Xbf[i4 * 4] = o;
            }
        }
        return;
    }
    int b = blockIdx.z, i0 = blockIdx.y * 64, j0 = blockIdx.x * 64;
    __shared__ float hi[64][FOBS + 1];
    __shared__ float hj[64][FOBS + 1];
    __shared__ float av[FOBS];
    __shared__ float part_s[64][16];
    const float* Xb = X + (size_t)b * NN * FF;
    if (j0 == 0) {                                // Xo passthrough for this row-panel
#pragma unroll
        for (int p = 0; p < 8; p++) {
            int c = p * 256 + tid, r = c >> 5, qq = c & 31;
            *(float4*)&Xo[((size_t)b * NN + i0 + r) * FF + qq * 4] =
                *(const float4*)&Xb[(size_t)(i0 + r) * FF + qq * 4];
        }
    }
#pragma unroll
    for (int l = 0; l < 8; l++) {
        int idx = l * 256 + tid;
        int r = idx >> 5, f = idx & 31;
        hi[r][f] = Xb[(size_t)(i0 + r) * FF + f];
        hj[r][f] = Xb[(size_t)(j0 + r) * FF + f];
    }
    if (tid < FOBS) av[tid] = a_link[tid];
    __syncthreads();

    int ty = tid >> 4, tx = tid & 15;
    int ir = ty * 4, jc = tx * 4;
    float acc[4][4] = {};
#pragma unroll
    for (int f = 0; f < FOBS; f++) {
        float a = av[f];
        float x[4], y[4];
#pragma unroll
        for (int r = 0; r < 4; r++) x[r] = hi[ir + r][f];
#pragma unroll
        for (int c = 0; c < 4; c++) y[c] = hj[jc + c][f];
#pragma unroll
        for (int r = 0; r < 4; r++)
#pragma unroll
            for (int c = 0; c < 4; c++)
                acc[r][c] += fabsf(x[r] - y[c]) * a;
    }
    float* Ab = As + (size_t)b * NN * NN;
#pragma unroll
    for (int r = 0; r < 4; r++) {
        int gi = i0 + ir + r;
        float vv[4]; float rs = 0.f;
#pragma unroll
        for (int c = 0; c < 4; c++) {
            int gj = j0 + jc + c;
            float sg = 1.f / (1.f + __expf(-acc[r][c]));
            vv[c] = (gi == gj) ? 0.f : sg;
            rs += vv[c];
        }
        *(float4*)&Ab[(size_t)gi * NN + (j0 + jc)] = make_float4(vv[0], vv[1], vv[2], vv[3]);
        part_s[ir + r][tx] = rs;
    }
    __syncthreads();
    if (tid < 64) {                               // 16 partials -> one f32 per row
        float s = 0.f;
#pragma unroll
        for (int k = 0; k < 16; k++) s += part_s[tid][k];
        Pp[((size_t)b * NN + i0 + tid) * 16 + blockIdx.x] = s;
    }
}

// ---------------------------------------------------------------- t0 (MFMA) + dinv
// T0[f2][n] = sum_g W2t[f2][g] * sum_f W01t[g][f] * Xbf[n][f]    (= (X W0 W1 W2)^T)
// dinvG[b*N+n] = rsqrt(1 + rowsum) from Pp partials (16 rows per block).
__global__ __launch_bounds__(256) void t0_kernel(const unsigned short* __restrict__ Xbf,
                                                 const unsigned short* __restrict__ W01t,
                                                 const unsigned short* __restrict__ W2t,
                                                 const float* __restrict__ Pp,
                                                 unsigned short* __restrict__ TtX,
                                                 float* __restrict__ dinvG) {
    int bid = blockIdx.x;
    int b = bid >> 6, n0 = (bid & 63) * 16;
    __shared__ unsigned short W01s[128 * 128];
    __shared__ unsigned short W2s[128 * 128];
    __shared__ unsigned short Xps[16 * 128];
    __shared__ unsigned short Ps[16 * 128];
    int tid = threadIdx.x;
    const unsigned short* Xb = Xbf + (size_t)b * NN * DD;
#pragma unroll
    for (int p = 0; p < 8; p++) {
        int c = p * 256 + tid, row = c >> 4, kc = c & 15;
        gload16(W01t + (size_t)row * 128 + ((kc ^ (row & 7)) * 8), W01s + (size_t)c * 8);
    }
#pragma unroll
    for (int p = 0; p < 8; p++) {
        int c = p * 256 + tid, row = c >> 4, kc = c & 15;
        gload16(W2t + (size_t)row * 128 + ((kc ^ (row & 7)) * 8), W2s + (size_t)c * 8);
    }
    {
        int c = tid, row = c >> 4, kc = c & 15;
        gload16(Xb + (size_t)(n0 + row) * 128 + ((kc ^ (row & 7)) * 8), Xps + (size_t)c * 8);
    }
    {                                             // dinv for rows n0..n0+15
        int r = tid >> 4, p = tid & 15;
        float s = Pp[((size_t)b * NN + n0 + r) * 16 + p];
        s += __shfl_xor(s, 1);
        s += __shfl_xor(s, 2);
        s += __shfl_xor(s, 4);
        s += __shfl_xor(s, 8);
        if (p == 0) dinvG[(size_t)b * NN + n0 + r] = rsqrtf(1.f + s);
    }
    __syncthreads();

    int w = tid >> 6, l = tid & 63, lr = l & 15, lg = l >> 4;
    ffrag pacc[2] = {};                           // P[g][n] = (X @ W01)^T
#pragma unroll
    for (int ks = 0; ks < 4; ks++) {
        int k0 = ks * 32 + lg * 8;
        bfrag a[2], bb;
#pragma unroll
        for (int rb = 0; rb < 2; rb++) {
            int row = w * 32 + rb * 16 + lr;
            int byt = (row * 256 + k0 * 2) ^ ((row & 7) << 4);
            a[rb] = *(const bfrag*)((const char*)W01s + byt);
        }
        {
            int byt = (lr * 256 + k0 * 2) ^ ((lr & 7) << 4);
            bb = *(const bfrag*)((const char*)Xps + byt);
        }
#pragma unroll
        for (int rb = 0; rb < 2; rb++)
            pacc[rb] = __builtin_amdgcn_mfma_f32_16x16x32_bf16(a[rb], bb, pacc[rb], 0, 0, 0);
    }
#pragma unroll
    for (int rb = 0; rb < 2; rb++) {              // P -> LDS [n][g] swizzled
        int g0 = w * 32 + rb * 16 + lg * 4;
        us4 o;
#pragma unroll
        for (int r = 0; r < 4; r++) o[r] = f2bf(pacc[rb][r]);
        int byt = (lr * 256 + g0 * 2) ^ ((lr & 7) << 4);
        *(us4*)((char*)Ps + byt) = o;
    }
    __syncthreads();
    ffrag tacc[2] = {};                           // T0[f2][n] = (P^T @ W2)^T
#pragma unroll
    for (int ks = 0; ks < 4; ks++) {
        int k0 = ks * 32 + lg * 8;
        bfrag a2[2], b2;
#pragma unroll
        for (int rb = 0; rb < 2; rb++) {
            int row = w * 32 + rb * 16 + lr;
            int byt = (row * 256 + k0 * 2) ^ ((row & 7) << 4);
            a2[rb] = *(const bfrag*)((const char*)W2s + byt);
        }
        {
            int byt = (lr * 256 + k0 * 2) ^ ((lr & 7) << 4);
            b2 = *(const bfrag*)((const char*)Ps + byt);
        }
#pragma unroll
        for (int rb = 0; rb < 2; rb++)
            tacc[rb] = __builtin_amdgcn_mfma_f32_16x16x32_bf16(a2[rb], b2, tacc[rb], 0, 0, 0);
    }
    unsigned short* Tb = TtX + (size_t)b * DD * NN;
#pragma unroll
    for (int rb = 0; rb < 2; rb++)
#pragma unroll
        for (int r = 0; r < 4; r++) {
            int f2 = w * 32 + rb * 16 + lg * 4 + r;
            Tb[(size_t)f2 * NN + n0 + lr] = f2bf(tacc[rb][r]);
        }
}

// ---------------------------------------------------------------- ga (pure S-GEMM, S in LDS)
// acc[f][n] = sum_k T[f][k] * S[k][n], S symmetric, rows n0..n0+15 rebuilt in LDS
// from As(f32)+dinv:  S[i][j] = dinv_i*dinv_j*(A[i][j] + (i==j)).
// LAST=0: Tout[f][n]=bf16(acc);  LAST=1: Hs[n][f]=relu(acc) f32.
template <int LAST>
__global__ __launch_bounds__(256) void ga_kernel(const float* __restrict__ As,
                                                 const float* __restrict__ dinvG,
                                                 const unsigned short* __restrict__ Tin,
                                                 unsigned short* __restrict__ Tout,
                                                 float* __restrict__ HsF) {
    int bid = blockIdx.x;
    int b = bid >> 6, n0 = (bid & 63) * 16;
    __shared__ unsigned short T_s[3 * 128 * 64];   // 49152 B
    __shared__ unsigned short S_s[16 * 1024];      // 32768 B, swizzled rows (stride 2048B)
    __shared__ float dinvF[NN];                    // 4096 B
    int tid = threadIdx.x;
    const unsigned short* Tb = Tin + (size_t)b * DD * NN;

    auto stageT = [&](int buf, int kt) {           // 4 gload16 per thread
#pragma unroll
        for (int p = 0; p < 4; p++) {
            int c = p * 256 + tid, row = c >> 3, kc = c & 7;
            gload16(Tb + (size_t)row * NN + kt + ((kc ^ (row & 7)) * 8),
                    T_s + (size_t)buf * (128 * 64) + (size_t)c * 8);
        }
    };
    stageT(0, 0);                                  // prefetch overlaps S-build latency
    stageT(1, 64);

    {                                              // dinv -> LDS
        *(float4*)&dinvF[tid * 4] = *(const float4*)&dinvG[(size_t)b * NN + tid * 4];
    }
    __syncthreads();
    {                                              // build 16 S rows into LDS
        int row = tid >> 4, gi = n0 + row;
        const float* Ar = As + ((size_t)b * NN + gi) * NN;
        float di = dinvF[gi];
#pragma unroll
        for (int cc = 0; cc < 16; cc++) {
            int col = (tid & 15) * 4 + cc * 64;
            float4 a4 = *(const float4*)&Ar[col];
            us4 o;
            o[0] = f2bf(di * dinvF[col + 0] * (a4.x + ((col + 0) == gi ? 1.f : 0.f)));
            o[1] = f2bf(di * dinvF[col + 1] * (a4.y + ((col + 1) == gi ? 1.f : 0.f)));
            o[2] = f2bf(di * dinvF[col + 2] * (a4.z + ((col + 2) == gi ? 1.f : 0.f)));
            o[3] = f2bf(di * dinvF[col + 3] * (a4.w + ((col + 3) == gi ? 1.f : 0.f)));
            int byt = (row * 2048 + col * 2) ^ ((row & 7) << 4);
            *(us4*)((char*)S_s + byt) = o;
        }
    }
    __syncthreads();                               // S ready (also drains st0/st1 — ok)

    int w = tid >> 6, l = tid & 63, lr = l & 15, lg = l >> 4;
    ffrag acc[2] = {};
    int cur = 0, sb = 2;
    for (int t = 0; t < 16; t++) {
        if (t <= 13) stageT(sb, (t + 2) * 64);
        if (t < 14)       asm volatile("s_waitcnt vmcnt(8)" ::: "memory");
        else if (t == 14) asm volatile("s_waitcnt vmcnt(4)" ::: "memory");
        else              asm volatile("s_waitcnt vmcnt(0)" ::: "memory");
        __builtin_amdgcn_s_barrier();
        asm volatile("" ::: "memory");
        const unsigned short* Tc = T_s + (size_t)cur * (128 * 64);
#pragma unroll
        for (int ks = 0; ks < 2; ks++) {
            int k0 = ks * 32 + lg * 8;
            int kg = t * 64 + k0;                  // global k for S row read
            bfrag a[2], bb;
#pragma unroll
            for (int rb = 0; rb < 2; rb++) {
                int row = w * 32 + rb * 16 + lr;
                int byt = (row * 128 + k0 * 2) ^ ((row & 7) << 4);
                a[rb] = *(const bfrag*)((const char*)Tc + byt);
            }
            {
                int byt = (lr * 2048 + kg * 2) ^ ((lr & 7) << 4);
                bb = *(const bfrag*)((const char*)S_s + byt);
            }
#pragma unroll
            for (int rb = 0; rb < 2; rb++)
                acc[rb] = __builtin_amdgcn_mfma_f32_16x16x32_bf16(a[rb], bb, acc[rb], 0, 0, 0);
        }
        asm volatile("s_waitcnt lgkmcnt(0)" ::: "memory");
        __builtin_amdgcn_s_barrier();              // all reads of buf done before overwrite
        cur = (cur == 2) ? 0 : cur + 1;
        sb = (sb == 2) ? 0 : sb + 1;
    }

    if (LAST) {                                    // relu, f32, node-major
#pragma unroll
        for (int rb = 0; rb < 2; rb++) {
            int f0 = w * 32 + rb * 16 + lg * 4;
            float v[4];
#pragma unroll
            for (int r = 0; r < 4; r++) v[r] = fmaxf(acc[rb][r], 0.f);
            *(float4*)&HsF[((size_t)b * NN + n0 + lr) * DD + f0] = make_float4(v[0], v[1], v[2], v[3]);
        }
    } else {
        unsigned short* Ob = Tout + (size_t)b * DD * NN;
#pragma unroll
        for (int rb = 0; rb < 2; rb++)
#pragma unroll
            for (int r = 0; r < 4; r++) {
                int f = w * 32 + rb * 16 + lg * 4 + r;
                Ob[(size_t)f * NN + n0 + lr] = f2bf(acc[rb][r]);
            }
    }
}

// ---------------------------------------------------------------- launcher
extern "C" void kernel_launch(void* const* d_in, const int* in_sizes, int n_in,
                              void* d_out, int out_size, void* d_ws, size_t ws_size,
                              hipStream_t stream) {
    const float* X      = (const float*)d_in[0];
    const float* a_link = (const float*)d_in[1];
    const float* W0     = (const float*)d_in[2];
    const float* W1     = (const float*)d_in[3];
    const float* W2     = (const float*)d_in[4];
    float* out = (float*)d_out;

    const size_t HND = (size_t)BB * NN * DD;      // 524288
    const size_t HNN = (size_t)BB * NN * NN;      // 4194304
    float* Hs = out;
    float* As = out + HND;
    float* Xo = out + HND + HNN;
    float* Ds = out + 2 * HND + HNN;

    // scratch (bytes): Xbf 1048576 | TtX 1048576 | TtY 1048576 | W01t 32768
    //                  | W2t 32768 | Pp 262144 | dinvG 16384  => 3,489,792
    const size_t NEED = 3489792;
    bool usews = (ws_size >= NEED);
    char* scr = usews ? (char*)d_ws : (char*)Ds;

    unsigned short* Xbf  = (unsigned short*)(scr);
    unsigned short* TtX  = (unsigned short*)(scr + 1048576);
    unsigned short* TtY  = (unsigned short*)(scr + 2097152);
    unsigned short* W01t = (unsigned short*)(scr + 3145728);
    unsigned short* W2t  = (unsigned short*)(scr + 3178496);
    float* Pp            = (float*)(scr + 3211264);
    float* dinvG         = (float*)(scr + 3473408);

    adj_kernel<<<dim3(16, 16, usews ? 6 : 5), 256, 0, stream>>>(
        X, a_link, W0, W1, W2, As, Xbf, W01t, W2t, Pp, Xo, usews ? Ds : nullptr);
    t0_kernel<<<dim3(256), 256, 0, stream>>>(Xbf, W01t, W2t, Pp, TtX, dinvG);
    ga_kernel<0><<<dim3(256), 256, 0, stream>>>(As, dinvG, TtX, TtY, nullptr);
    ga_kernel<0><<<dim3(256), 256, 0, stream>>>(As, dinvG, TtY, TtX, nullptr);
    ga_kernel<1><<<dim3(256), 256, 0, stream>>>(As, dinvG, TtX, nullptr, Hs);

    if (!usews)                                    // scratch lived in Ds: zero it now
        zero_f4<<<dim3(4096), 256, 0, stream>>>((float4*)Ds, (int)(HNN / 4));
}

// Round 9
// 50.538 us; speedup vs baseline: 3.0900x; 1.1212x over previous
//
#include <hip/hip_runtime.h>
#include <math.h>

#define BB 4
#define NN 1024
#define FF 128
#define DD 128
#define FOBS 32

typedef __attribute__((ext_vector_type(8))) short bfrag;   // 8 bf16 = 4 VGPR
typedef __attribute__((ext_vector_type(4))) float ffrag;   // 4 f32 acc
typedef __attribute__((ext_vector_type(4))) unsigned short us4;

__device__ __forceinline__ unsigned short f2bf(float x) {
    unsigned u = __builtin_bit_cast(unsigned, x);
    u += 0x7fffu + ((u >> 16) & 1u);              // RNE
    return (unsigned short)(u >> 16);
}
__device__ __forceinline__ float bf2f(unsigned short s) {
    unsigned u = (unsigned)s << 16;
    return __builtin_bit_cast(float, u);
}
__device__ __forceinline__ void gload16(const void* g, void* l) {
    __builtin_amdgcn_global_load_lds((const __attribute__((address_space(1))) unsigned*)g,
                                     (__attribute__((address_space(3))) unsigned*)l, 16, 0, 0);
}

// ---------------------------------------------------------------- zero (f4)  (fallback)
__global__ __launch_bounds__(256) void zero_f4(float4* __restrict__ p, int n4) {
    int i = blockIdx.x * 256 + threadIdx.x;
    if (i < n4) p[i] = make_float4(0.f, 0.f, 0.f, 0.f);
}

// ---------------------------------------------------------------- adjacency (+prep +partials +Xo +Ds-zero)
// z 0..3 : A 64x64 tiles -> As f32 (output) + Abf bf16 (GEMM operand) + Pp partial row-sums
// z 4    : prep — W01t[g][f]=(W0@W1)[f][g] bf16; W2t[f2][g]=W2[g][f2] bf16; Xbf cast
// z 5    : Ds-zero (only when scratch lives in d_ws)
__global__ __launch_bounds__(256) void adj_kernel(const float* __restrict__ X,
                                                  const float* __restrict__ a_link,
                                                  const float* __restrict__ W0,
                                                  const float* __restrict__ W1,
                                                  const float* __restrict__ W2,
                                                  float* __restrict__ As,
                                                  unsigned short* __restrict__ Abf,
                                                  unsigned short* __restrict__ Xbf,
                                                  unsigned short* __restrict__ W01t,
                                                  unsigned short* __restrict__ W2t,
                                                  float* __restrict__ Pp,
                                                  float* __restrict__ Xo,
                                                  float* __restrict__ Zd) {
    int tid = threadIdx.x;
    if (blockIdx.z == 5) {                        // Ds-zero layer
        if (Zd) {
            int q = blockIdx.y * 16 + blockIdx.x; // 0..255
            float4* Z = (float4*)Zd;
#pragma unroll
            for (int p = 0; p < 16; p++)
                Z[(size_t)q * 4096 + p * 256 + tid] = make_float4(0.f, 0.f, 0.f, 0.f);
        }
        return;
    }
    if (blockIdx.z == 4) {                        // prep
        int q = (blockIdx.y * 16 + blockIdx.x) * 256 + tid;   // 0..65535
        if (q < 16384) {                          // W01t[g][f] = sum_h W0[f][h]*W1[h][g]
            int g = q >> 7, f = q & 127;
            float s = 0.f;
            for (int h = 0; h < 128; h++) s += W0[f * 128 + h] * W1[h * 128 + g];
            W01t[q] = f2bf(s);
        } else if (q < 32768) {                   // W2t[f2][g] = W2[g][f2]
            int e = q - 16384;
            int f2 = e >> 7, g = e & 127;
            W2t[e] = f2bf(W2[g * 128 + f2]);
        } else {                                  // Xbf cast: 32768 thr x 4 float4
            int u = q - 32768;
#pragma unroll
            for (int p = 0; p < 4; p++) {
                size_t i4 = (size_t)u + (size_t)p * 32768;
                float4 v = *(const float4*)&X[i4 * 4];
                us4 o; o[0] = f2bf(v.x); o[1] = f2bf(v.y); o[2] = f2bf(v.z); o[3] = f2bf(v.w);
                *(us4*)&Xbf[i4 * 4] = o;
            }
        }
        return;
    }
    int b = blockIdx.z, i0 = blockIdx.y * 64, j0 = blockIdx.x * 64;
    __shared__ float hi[64][FOBS + 1];
    __shared__ float hj[64][FOBS + 1];
    __shared__ float av[FOBS];
    __shared__ float part_s[64][16];
    const float* Xb = X + (size_t)b * NN * FF;
    if (j0 == 0) {                                // Xo passthrough for this row-panel
#pragma unroll
        for (int p = 0; p < 8; p++) {
            int c = p * 256 + tid, r = c >> 5, qq = c & 31;
            *(float4*)&Xo[((size_t)b * NN + i0 + r) * FF + qq * 4] =
                *(const float4*)&Xb[(size_t)(i0 + r) * FF + qq * 4];
        }
    }
#pragma unroll
    for (int l = 0; l < 8; l++) {
        int idx = l * 256 + tid;
        int r = idx >> 5, f = idx & 31;
        hi[r][f] = Xb[(size_t)(i0 + r) * FF + f];
        hj[r][f] = Xb[(size_t)(j0 + r) * FF + f];
    }
    if (tid < FOBS) av[tid] = a_link[tid];
    __syncthreads();

    int ty = tid >> 4, tx = tid & 15;
    int ir = ty * 4, jc = tx * 4;
    float acc[4][4] = {};
#pragma unroll
    for (int f = 0; f < FOBS; f++) {
        float a = av[f];
        float x[4], y[4];
#pragma unroll
        for (int r = 0; r < 4; r++) x[r] = hi[ir + r][f];
#pragma unroll
        for (int c = 0; c < 4; c++) y[c] = hj[jc + c][f];
#pragma unroll
        for (int r = 0; r < 4; r++)
#pragma unroll
            for (int c = 0; c < 4; c++)
                acc[r][c] += fabsf(x[r] - y[c]) * a;
    }
    float* Ab = As + (size_t)b * NN * NN;
    unsigned short* Abb = Abf + (size_t)b * NN * NN;
#pragma unroll
    for (int r = 0; r < 4; r++) {
        int gi = i0 + ir + r;
        float vv[4]; float rs = 0.f;
#pragma unroll
        for (int c = 0; c < 4; c++) {
            int gj = j0 + jc + c;
            float sg = 1.f / (1.f + __expf(-acc[r][c]));
            vv[c] = (gi == gj) ? 0.f : sg;
            rs += vv[c];
        }
        *(float4*)&Ab[(size_t)gi * NN + (j0 + jc)] = make_float4(vv[0], vv[1], vv[2], vv[3]);
        us4 o; o[0] = f2bf(vv[0]); o[1] = f2bf(vv[1]); o[2] = f2bf(vv[2]); o[3] = f2bf(vv[3]);
        *(us4*)&Abb[(size_t)gi * NN + (j0 + jc)] = o;
        part_s[ir + r][tx] = rs;
    }
    __syncthreads();
    if (tid < 64) {                               // 16 partials -> one f32 per row
        float s = 0.f;
#pragma unroll
        for (int k = 0; k < 16; k++) s += part_s[tid][k];
        Pp[((size_t)b * NN + i0 + tid) * 16 + blockIdx.x] = s;
    }
}

// ---------------------------------------------------------------- t0 (MFMA)
// T0[f2][n] = dinv[n] * sum_g W2t[f2][g] * sum_f W01t[g][f] * Xbf[n][f]
//           = (D^-1/2 X W0 W1 W2)^T  -- the z0 panel.
__global__ __launch_bounds__(256) void t0_kernel(const unsigned short* __restrict__ Xbf,
                                                 const unsigned short* __restrict__ W01t,
                                                 const unsigned short* __restrict__ W2t,
                                                 const float* __restrict__ Pp,
                                                 unsigned short* __restrict__ TtX) {
    int bid = blockIdx.x;
    int b = bid >> 6, n0 = (bid & 63) * 16;
    __shared__ unsigned short W01s[128 * 128];
    __shared__ unsigned short W2s[128 * 128];
    __shared__ unsigned short Xps[16 * 128];
    __shared__ unsigned short Ps[16 * 128];
    __shared__ float dinv_s[16];
    int tid = threadIdx.x;
    const unsigned short* Xb = Xbf + (size_t)b * NN * DD;
    {                                             // dinv for rows n0..n0+15 (drains its load)
        int r = tid >> 4, p = tid & 15;
        float s = Pp[((size_t)b * NN + n0 + r) * 16 + p];
        s += __shfl_xor(s, 1);
        s += __shfl_xor(s, 2);
        s += __shfl_xor(s, 4);
        s += __shfl_xor(s, 8);
        if (p == 0) dinv_s[r] = rsqrtf(1.f + s);
    }
#pragma unroll
    for (int p = 0; p < 8; p++) {
        int c = p * 256 + tid, row = c >> 4, kc = c & 15;
        gload16(W01t + (size_t)row * 128 + ((kc ^ (row & 7)) * 8), W01s + (size_t)c * 8);
    }
#pragma unroll
    for (int p = 0; p < 8; p++) {
        int c = p * 256 + tid, row = c >> 4, kc = c & 15;
        gload16(W2t + (size_t)row * 128 + ((kc ^ (row & 7)) * 8), W2s + (size_t)c * 8);
    }
    {
        int c = tid, row = c >> 4, kc = c & 15;
        gload16(Xb + (size_t)(n0 + row) * 128 + ((kc ^ (row & 7)) * 8), Xps + (size_t)c * 8);
    }
    __syncthreads();

    int w = tid >> 6, l = tid & 63, lr = l & 15, lg = l >> 4;
    ffrag pacc[2] = {};                           // P[g][n] = (X @ W01)^T
#pragma unroll
    for (int ks = 0; ks < 4; ks++) {
        int k0 = ks * 32 + lg * 8;
        bfrag a[2], bb;
#pragma unroll
        for (int rb = 0; rb < 2; rb++) {
            int row = w * 32 + rb * 16 + lr;
            int byt = (row * 256 + k0 * 2) ^ ((row & 7) << 4);
            a[rb] = *(const bfrag*)((const char*)W01s + byt);
        }
        {
            int byt = (lr * 256 + k0 * 2) ^ ((lr & 7) << 4);
            bb = *(const bfrag*)((const char*)Xps + byt);
        }
#pragma unroll
        for (int rb = 0; rb < 2; rb++)
            pacc[rb] = __builtin_amdgcn_mfma_f32_16x16x32_bf16(a[rb], bb, pacc[rb], 0, 0, 0);
    }
#pragma unroll
    for (int rb = 0; rb < 2; rb++) {              // P -> LDS [n][g] swizzled
        int g0 = w * 32 + rb * 16 + lg * 4;
        us4 o;
#pragma unroll
        for (int r = 0; r < 4; r++) o[r] = f2bf(pacc[rb][r]);
        int byt = (lr * 256 + g0 * 2) ^ ((lr & 7) << 4);
        *(us4*)((char*)Ps + byt) = o;
    }
    __syncthreads();
    ffrag tacc[2] = {};                           // y0[f2][n] = (P^T @ W2)^T
#pragma unroll
    for (int ks = 0; ks < 4; ks++) {
        int k0 = ks * 32 + lg * 8;
        bfrag a2[2], b2;
#pragma unroll
        for (int rb = 0; rb < 2; rb++) {
            int row = w * 32 + rb * 16 + lr;
            int byt = (row * 256 + k0 * 2) ^ ((row & 7) << 4);
            a2[rb] = *(const bfrag*)((const char*)W2s + byt);
        }
        {
            int byt = (lr * 256 + k0 * 2) ^ ((lr & 7) << 4);
            b2 = *(const bfrag*)((const char*)Ps + byt);
        }
#pragma unroll
        for (int rb = 0; rb < 2; rb++)
            tacc[rb] = __builtin_amdgcn_mfma_f32_16x16x32_bf16(a2[rb], b2, tacc[rb], 0, 0, 0);
    }
    unsigned short* Tb = TtX + (size_t)b * DD * NN;
    float dv = dinv_s[lr];
#pragma unroll
    for (int rb = 0; rb < 2; rb++)
#pragma unroll
        for (int r = 0; r < 4; r++) {
            int f2 = w * 32 + rb * 16 + lg * 4 + r;
            Tb[(size_t)f2 * NN + n0 + lr] = f2bf(tacc[rb][r] * dv);
        }
}

// ---------------------------------------------------------------- ga (pipelined A-GEMM, split-f)
// Block (panel, fh): 64 f-rows (fh half), 16 n-cols.  acc = sum_k T[f][k]*A[k][n]
// (A symmetric -> stage A[n][k] rows contiguous).  Epilogue:
//   LAST=0: Tout[f][n] = dinv[n]^2 * (acc + Tin[f][n])      (z_{i+1} = D^-1 Â z_i)
//   LAST=1: Hs[n][f]   = relu(dinv[n] * (acc + Tin[f][n]))  (H = D^-1/2 Â z2)
template <int LAST>
__global__ __launch_bounds__(256) void ga_kernel(const unsigned short* __restrict__ Abf,
                                                 const float* __restrict__ Pp,
                                                 const unsigned short* __restrict__ Tin,
                                                 unsigned short* __restrict__ Tout,
                                                 float* __restrict__ HsF) {
    int bid = blockIdx.x;
    int fh = bid & 1, panel = bid >> 1;
    int b = panel >> 6, n0 = (panel & 63) * 16;
    __shared__ unsigned short T_s[3 * 64 * 64];   // 24 KB
    __shared__ unsigned short A_s[3 * 16 * 64];   // 6 KB
    __shared__ float dinv_s[16];
    int tid = threadIdx.x;
    const unsigned short* TbF = Tin + (size_t)b * DD * NN;       // full panel (identity reads)
    const unsigned short* Tb  = TbF + (size_t)fh * 64 * NN;      // this block's f-half
    const unsigned short* Ab  = Abf + (size_t)b * NN * NN;

    {                                             // dinv for own 16 rows (drains its load)
        int r = tid >> 4, p = tid & 15;
        float s = Pp[((size_t)b * NN + n0 + r) * 16 + p];
        s += __shfl_xor(s, 1);
        s += __shfl_xor(s, 2);
        s += __shfl_xor(s, 4);
        s += __shfl_xor(s, 8);
        if (p == 0) dinv_s[r] = rsqrtf(1.f + s);
    }
    auto stageT = [&](int buf, int kt) {          // uniform 3 gload16 per thread
#pragma unroll
        for (int p = 0; p < 2; p++) {
            int c = p * 256 + tid, row = c >> 3, kc = c & 7;
            gload16(Tb + (size_t)row * NN + kt + ((kc ^ (row & 7)) * 8),
                    T_s + (size_t)buf * (64 * 64) + (size_t)c * 8);
        }
        int c = tid & 127, row = c >> 3, kc = c & 7;   // tid>=128 duplicates, benign
        gload16(Ab + (size_t)(n0 + row) * NN + kt + ((kc ^ (row & 7)) * 8),
                A_s + (size_t)buf * (16 * 64) + (size_t)c * 8);
    };
    stageT(0, 0);
    stageT(1, 64);

    int w = tid >> 6, l = tid & 63, lr = l & 15, lg = l >> 4;
    ffrag acc = {};
    int cur = 0, sb = 2;
    for (int t = 0; t < 16; t++) {
        if (t <= 13) stageT(sb, (t + 2) * 64);
        if (t < 14)       asm volatile("s_waitcnt vmcnt(6)" ::: "memory");
        else if (t == 14) asm volatile("s_waitcnt vmcnt(3)" ::: "memory");
        else              asm volatile("s_waitcnt vmcnt(0)" ::: "memory");
        __builtin_amdgcn_s_barrier();
        asm volatile("" ::: "memory");
        const unsigned short* Tc = T_s + (size_t)cur * (64 * 64);
        const unsigned short* Ac = A_s + (size_t)cur * (16 * 64);
#pragma unroll
        for (int ks = 0; ks < 2; ks++) {
            int k0 = ks * 32 + lg * 8;
            bfrag a, bb;
            {
                int row = w * 16 + lr;
                int byt = (row * 128 + k0 * 2) ^ ((row & 7) << 4);
                a = *(const bfrag*)((const char*)Tc + byt);
            }
            {
                int byt = (lr * 128 + k0 * 2) ^ ((lr & 7) << 4);
                bb = *(const bfrag*)((const char*)Ac + byt);
            }
            acc = __builtin_amdgcn_mfma_f32_16x16x32_bf16(a, bb, acc, 0, 0, 0);
        }
        asm volatile("s_waitcnt lgkmcnt(0)" ::: "memory");
        __builtin_amdgcn_s_barrier();             // all reads of buf done before overwrite
        cur = (cur == 2) ? 0 : cur + 1;
        sb = (sb == 2) ? 0 : sb + 1;
    }

    int nl = lr;
    float dv = dinv_s[nl];
    int f0 = fh * 64 + w * 16 + lg * 4;
    if (LAST) {                                   // H = relu(dinv*(acc + z2)), f32 node-major
        float v[4];
#pragma unroll
        for (int r = 0; r < 4; r++) {
            float idv = bf2f(TbF[(size_t)(f0 + r) * NN + n0 + nl]);
            v[r] = fmaxf((acc[r] + idv) * dv, 0.f);
        }
        *(float4*)&HsF[((size_t)b * NN + n0 + nl) * DD + f0] = make_float4(v[0], v[1], v[2], v[3]);
    } else {                                      // z' = dinv^2*(acc + z)
        float dv2 = dv * dv;
        unsigned short* Ob = Tout + (size_t)b * DD * NN;
#pragma unroll
        for (int r = 0; r < 4; r++) {
            float idv = bf2f(TbF[(size_t)(f0 + r) * NN + n0 + nl]);
            Ob[(size_t)(f0 + r) * NN + n0 + nl] = f2bf((acc[r] + idv) * dv2);
        }
    }
}

// ---------------------------------------------------------------- launcher
extern "C" void kernel_launch(void* const* d_in, const int* in_sizes, int n_in,
                              void* d_out, int out_size, void* d_ws, size_t ws_size,
                              hipStream_t stream) {
    const float* X      = (const float*)d_in[0];
    const float* a_link = (const float*)d_in[1];
    const float* W0     = (const float*)d_in[2];
    const float* W1     = (const float*)d_in[3];
    const float* W2     = (const float*)d_in[4];
    float* out = (float*)d_out;

    const size_t HND = (size_t)BB * NN * DD;      // 524288
    const size_t HNN = (size_t)BB * NN * NN;      // 4194304
    float* Hs = out;
    float* As = out + HND;
    float* Xo = out + HND + HNN;
    float* Ds = out + 2 * HND + HNN;

    // scratch (bytes): Abf 8388608 | Xbf 1048576 | TtX 1048576 | TtY 1048576
    //                  | W01t 32768 | W2t 32768 | Pp 262144  => 11,862,016
    const size_t NEED = 11862016;
    bool usews = (ws_size >= NEED);
    char* scr = usews ? (char*)d_ws : (char*)Ds;

    unsigned short* Abf  = (unsigned short*)(scr);
    unsigned short* Xbf  = (unsigned short*)(scr + 8388608);
    unsigned short* TtX  = (unsigned short*)(scr + 9437184);
    unsigned short* TtY  = (unsigned short*)(scr + 10485760);
    unsigned short* W01t = (unsigned short*)(scr + 11534336);
    unsigned short* W2t  = (unsigned short*)(scr + 11567104);
    float* Pp            = (float*)(scr + 11599872);

    adj_kernel<<<dim3(16, 16, usews ? 6 : 5), 256, 0, stream>>>(
        X, a_link, W0, W1, W2, As, Abf, Xbf, W01t, W2t, Pp, Xo, usews ? Ds : nullptr);
    t0_kernel<<<dim3(256), 256, 0, stream>>>(Xbf, W01t, W2t, Pp, TtX);
    ga_kernel<0><<<dim3(512), 256, 0, stream>>>(Abf, Pp, TtX, TtY, nullptr);
    ga_kernel<0><<<dim3(512), 256, 0, stream>>>(Abf, Pp, TtY, TtX, nullptr);
    ga_kernel<1><<<dim3(512), 256, 0, stream>>>(Abf, Pp, TtX, nullptr, Hs);

    if (!usews)                                    // scratch lived in Ds: zero it now
        zero_f4<<<dim3(4096), 256, 0, stream>>>((float4*)Ds, (int)(HNN / 4));
}